// Round 1
// baseline (366.767 us; speedup 1.0000x reference)
//
#include <hip/hip_runtime.h>
#include <stdint.h>

typedef __attribute__((ext_vector_type(4))) float f32x4;
typedef __attribute__((ext_vector_type(4))) float fvec4;
typedef __attribute__((ext_vector_type(8))) short bf16x8;
typedef __attribute__((ext_vector_type(4))) short s16x4;

#define DEVI static __device__ __forceinline__

constexpr int CB  = 4;     // batch
constexpr int CS  = 2048;  // seq
constexpr int CH  = 16;    // heads
constexpr int CDH = 64;    // head dim
constexpr int CE  = 1024;  // embed

DEVI short f2bf(float x) {  // RNE float->bf16
  unsigned u = __float_as_uint(x);
  u += 0x7fffu + ((u >> 16) & 1u);
  return (short)(u >> 16);
}

DEVI void gload16(const void* g, void* l) {
  __builtin_amdgcn_global_load_lds(
      (const __attribute__((address_space(1))) void*)g,
      (__attribute__((address_space(3))) void*)l, 16, 0, 0);
}

DEVI f32x4 mfma16(bf16x8 a, bf16x8 b, f32x4 c) {
  return __builtin_amdgcn_mfma_f32_16x16x32_bf16(a, b, c, 0, 0, 0);
}

// C[m,n] = sum_k A[m,k] * W[n,k] + bias[n]   (torch Linear, B^T form)
// ABF16: A is bf16 [M,K] (else fp32, converted during staging)
// MODE 0: out fp32 [M,N]
// MODE 1: out bf16 [B,H,S,DH]  (row=(b,s), col=(h,d)), value scaled
// MODE 2: out bf16 [B,H,DH,S]  (transposed for attention V)
template<int ABF16, int MODE>
__global__ __launch_bounds__(256) void gemm_bt(
    const void* __restrict__ Ap, const float* __restrict__ Wp,
    const float* __restrict__ bias, void* __restrict__ outp,
    int M, int N, int K, float scale)
{
  __shared__ short As[128 * 32];
  __shared__ short Bs[128 * 32];
  const int t  = threadIdx.x;
  const int l  = t & 63;
  const int w  = t >> 6;
  const int g  = l >> 4;
  const int ln = l & 15;
  const int m0 = blockIdx.y * 128;
  const int n0 = blockIdx.x * 128;
  const int wr = (w >> 1) * 64;
  const int wc = (w & 1) * 64;
  const f32x4 fzero = {0.f, 0.f, 0.f, 0.f};

  f32x4 acc[4][4];
#pragma unroll
  for (int i = 0; i < 4; ++i)
#pragma unroll
    for (int j = 0; j < 4; ++j) acc[i][j] = fzero;

  for (int kt = 0; kt < K; kt += 32) {
    if constexpr (ABF16) {
      const char* ab = (const char*)Ap;
#pragma unroll
      for (int il = 0; il < 2; ++il) {
        int o = (w * 2 + il) * 1024 + l * 16;
        int row = o >> 6, cb = o & 63;
        gload16(ab + ((size_t)(m0 + row) * K + kt) * 2 + cb, (char*)As + o);
      }
    } else {
      const float* A = (const float*)Ap;
#pragma unroll
      for (int i = 0; i < 4; ++i) {
        int c = (i << 8) + t;
        int row = c >> 3, col = (c & 7) << 2;
        fvec4 v = *(const fvec4*)&A[(size_t)(m0 + row) * K + kt + col];
        s16x4 s = {f2bf(v[0]), f2bf(v[1]), f2bf(v[2]), f2bf(v[3])};
        *(s16x4*)&As[row * 32 + col] = s;
      }
    }
#pragma unroll
    for (int i = 0; i < 4; ++i) {
      int c = (i << 8) + t;
      int row = c >> 3, col = (c & 7) << 2;
      fvec4 v = *(const fvec4*)&Wp[(size_t)(n0 + row) * K + kt + col];
      s16x4 s = {f2bf(v[0]), f2bf(v[1]), f2bf(v[2]), f2bf(v[3])};
      *(s16x4*)&Bs[row * 32 + col] = s;
    }
    __syncthreads();

    bf16x8 af[4], bfr[4];
#pragma unroll
    for (int mi = 0; mi < 4; ++mi)
      af[mi] = *(const bf16x8*)&As[(wr + mi * 16 + ln) * 32 + g * 8];
#pragma unroll
    for (int ni = 0; ni < 4; ++ni)
      bfr[ni] = *(const bf16x8*)&Bs[(wc + ni * 16 + ln) * 32 + g * 8];
#pragma unroll
    for (int mi = 0; mi < 4; ++mi)
#pragma unroll
      for (int ni = 0; ni < 4; ++ni)
        acc[mi][ni] = mfma16(af[mi], bfr[ni], acc[mi][ni]);
    __syncthreads();
  }

  // C/D layout: col = lane&15, row = (lane>>4)*4 + reg
#pragma unroll
  for (int mi = 0; mi < 4; ++mi)
#pragma unroll
    for (int ni = 0; ni < 4; ++ni)
#pragma unroll
      for (int r = 0; r < 4; ++r) {
        int row = m0 + wr + mi * 16 + g * 4 + r;
        int col = n0 + wc + ni * 16 + ln;
        float v = acc[mi][ni][r] + bias[col];
        if constexpr (MODE == 0) {
          ((float*)outp)[(size_t)row * N + col] = v;
        } else if constexpr (MODE == 1) {
          int b = row >> 11, s = row & 2047, h = col >> 6, d = col & 63;
          ((short*)outp)[(((size_t)(b * CH + h)) * CS + s) * CDH + d] =
              f2bf(v * scale);
        } else {
          int b = row >> 11, s = row & 2047, h = col >> 6, d = col & 63;
          ((short*)outp)[(((size_t)(b * CH + h)) * CDH + d) * CS + s] =
              f2bf(v * scale);
        }
      }
}

// Flash attention. q: [BH,S,DH] bf16 (pre-scaled by log2e/8), k: [BH,S,DH],
// vt: [BH,DH,S]. out: [B,S,E] bf16. Swapped QK^T (mfma(K,Q)) so each lane's
// softmax row (q = lane&15) is lane-local; P feeds PV A-operand directly.
__global__ __launch_bounds__(256) void attn_fwd(
    const short* __restrict__ qp, const short* __restrict__ kp,
    const short* __restrict__ vtp, short* __restrict__ outp)
{
  __shared__ short Ks[64 * 64];
  __shared__ short Vs[64 * 64];
  const int t  = threadIdx.x;
  const int l  = t & 63;
  const int w  = t >> 6;
  const int g  = l >> 4;
  const int ln = l & 15;
  const int qb = blockIdx.x;
  const int bh = blockIdx.y;
  const f32x4 fzero = {0.f, 0.f, 0.f, 0.f};

  // Q fragments (B-operand): lane ln = q row (within wave's 16), k = dh
  // assumed k-map (two-half): elem j -> k = 16*(j>>2) + g*4 + (j&3)
  const short* qrow = qp + ((size_t)bh * CS + qb * 64 + w * 16 + ln) * CDH;
  s16x4 qv0 = *(const s16x4*)&qrow[g * 4];
  s16x4 qv1 = *(const s16x4*)&qrow[16 + g * 4];
  s16x4 qv2 = *(const s16x4*)&qrow[32 + g * 4];
  s16x4 qv3 = *(const s16x4*)&qrow[48 + g * 4];
  bf16x8 qf0 = {qv0[0], qv0[1], qv0[2], qv0[3], qv1[0], qv1[1], qv1[2], qv1[3]};
  bf16x8 qf1 = {qv2[0], qv2[1], qv2[2], qv2[3], qv3[0], qv3[1], qv3[2], qv3[3]};

  f32x4 accO[4];
#pragma unroll
  for (int i = 0; i < 4; ++i) accO[i] = fzero;
  float mrun = -1e30f, lrun = 0.f;

  for (int kv0 = 0; kv0 < CS; kv0 += 64) {
    // Stage K[64 kv][64 d] and Vt[64 d][64 kv], XOR-swizzled via source addr.
#pragma unroll
    for (int il = 0; il < 2; ++il) {
      int o = (w * 2 + il) * 1024 + l * 16;
      int row = o >> 7, cb = o & 127;
      int lcb = cb ^ ((row & 7) << 4);
      gload16((const char*)kp + ((size_t)(bh * CS + kv0 + row)) * 128 + lcb,
              (char*)Ks + o);
      gload16((const char*)vtp + ((size_t)(bh * CDH + row)) * (CS * 2) +
                  kv0 * 2 + lcb,
              (char*)Vs + o);
    }
    __syncthreads();

    // QK^T swapped: D[kv][q], A = K rows (m=kv), B = Q (n=q)
    f32x4 sc[4];
#pragma unroll
    for (int c = 0; c < 4; ++c) {
      sc[c] = fzero;
      int row = c * 16 + ln;
      int sw = (row & 7) << 4;
#pragma unroll
      for (int st = 0; st < 2; ++st) {
        s16x4 a0 = *(const s16x4*)((const char*)Ks + row * 128 +
                                   ((st * 64 + g * 8) ^ sw));
        s16x4 a1 = *(const s16x4*)((const char*)Ks + row * 128 +
                                   ((st * 64 + 32 + g * 8) ^ sw));
        bf16x8 kf = {a0[0], a0[1], a0[2], a0[3], a1[0], a1[1], a1[2], a1[3]};
        sc[c] = mfma16(kf, st ? qf1 : qf0, sc[c]);
      }
    }

    // Online softmax (log2 domain; q-scale already includes log2e/8).
    // Lane's 16 values: kv = c*16 + g*4 + r for its q = ln.
    float pm = -1e30f;
#pragma unroll
    for (int c = 0; c < 4; ++c)
#pragma unroll
      for (int r = 0; r < 4; ++r) pm = fmaxf(pm, sc[c][r]);
    pm = fmaxf(pm, __shfl_xor(pm, 16, 64));
    pm = fmaxf(pm, __shfl_xor(pm, 32, 64));
    float mnew = fmaxf(mrun, pm);
    float fac = exp2f(mrun - mnew);
    float p[16];
    float ls = 0.f;
#pragma unroll
    for (int c = 0; c < 4; ++c)
#pragma unroll
      for (int r = 0; r < 4; ++r) {
        float e = exp2f(sc[c][r] - mnew);
        p[c * 4 + r] = e;
        ls += e;
      }
    lrun = lrun * fac + ls;
    mrun = mnew;

    // Rescale O: acc rows are q = g*4+r; factor lives in lane (g*4+r) (ln match)
    float facr[4];
#pragma unroll
    for (int r = 0; r < 4; ++r) facr[r] = __shfl(fac, g * 4 + r, 64);
#pragma unroll
    for (int nb = 0; nb < 4; ++nb)
#pragma unroll
      for (int r = 0; r < 4; ++r) accO[nb][r] *= facr[r];

    // P -> A-operand: slot j of step st <-> kv = st*32 + 16*(j>>2) + g*4 + (j&3)
    bf16x8 pa0 = {f2bf(p[0]),  f2bf(p[1]),  f2bf(p[2]),  f2bf(p[3]),
                  f2bf(p[4]),  f2bf(p[5]),  f2bf(p[6]),  f2bf(p[7])};
    bf16x8 pa1 = {f2bf(p[8]),  f2bf(p[9]),  f2bf(p[10]), f2bf(p[11]),
                  f2bf(p[12]), f2bf(p[13]), f2bf(p[14]), f2bf(p[15])};

    // PV: D[q][dh], B = Vt rows (n=dh), k = kv
#pragma unroll
    for (int nb = 0; nb < 4; ++nb) {
      int vrow = nb * 16 + ln;
      int sw = (vrow & 7) << 4;
#pragma unroll
      for (int st = 0; st < 2; ++st) {
        s16x4 b0 = *(const s16x4*)((const char*)Vs + vrow * 128 +
                                   ((st * 64 + g * 8) ^ sw));
        s16x4 b1 = *(const s16x4*)((const char*)Vs + vrow * 128 +
                                   ((st * 64 + 32 + g * 8) ^ sw));
        bf16x8 vf = {b0[0], b0[1], b0[2], b0[3], b1[0], b1[1], b1[2], b1[3]};
        accO[nb] = mfma16(st ? pa1 : pa0, vf, accO[nb]);
      }
    }
    __syncthreads();
  }

  lrun += __shfl_xor(lrun, 16, 64);
  lrun += __shfl_xor(lrun, 32, 64);
  float inv = 1.f / lrun;
  float invr[4];
#pragma unroll
  for (int r = 0; r < 4; ++r) invr[r] = __shfl(inv, g * 4 + r, 64);
  const int b = bh >> 4, h = bh & 15;
#pragma unroll
  for (int nb = 0; nb < 4; ++nb)
#pragma unroll
    for (int r = 0; r < 4; ++r) {
      int s = qb * 64 + w * 16 + g * 4 + r;
      float v = accO[nb][r] * invr[r];
      outp[((size_t)(b * CS + s)) * CE + h * CDH + nb * 16 + ln] = f2bf(v);
    }
}

extern "C" void kernel_launch(void* const* d_in, const int* in_sizes, int n_in,
                              void* d_out, int out_size, void* d_ws,
                              size_t ws_size, hipStream_t stream) {
  const float* queries = (const float*)d_in[0];
  const float* keys    = (const float*)d_in[1];
  const float* values  = (const float*)d_in[2];
  const float* Wq = (const float*)d_in[3];
  const float* bq = (const float*)d_in[4];
  const float* Wk = (const float*)d_in[5];
  const float* bk = (const float*)d_in[6];
  const float* Wv = (const float*)d_in[7];
  const float* bv = (const float*)d_in[8];
  const float* Wo = (const float*)d_in[9];
  const float* bo = (const float*)d_in[10];

  const size_t NELT = (size_t)CB * CS * CE;  // 8388608
  short* qp   = (short*)d_ws;
  short* kp   = qp + NELT;
  short* vtp  = kp + NELT;
  short* attn = vtp + NELT;

  dim3 blk(256);
  dim3 gproj(CE / 128, (CB * CS) / 128);  // (8, 64)
  const float qscale = 0.18033688011112042f;  // log2(e) / sqrt(DH)

  gemm_bt<0, 1><<<gproj, blk, 0, stream>>>(queries, Wq, bq, qp,
                                           CB * CS, CE, CE, qscale);
  gemm_bt<0, 1><<<gproj, blk, 0, stream>>>(keys, Wk, bk, kp,
                                           CB * CS, CE, CE, 1.0f);
  gemm_bt<0, 2><<<gproj, blk, 0, stream>>>(values, Wv, bv, vtp,
                                           CB * CS, CE, CE, 1.0f);
  attn_fwd<<<dim3(CS / 64, CB * CH), blk, 0, stream>>>(qp, kp, vtp, attn);
  gemm_bt<1, 0><<<gproj, blk, 0, stream>>>(attn, Wo, bo, (float*)d_out,
                                           CB * CS, CE, CE, 1.0f);
}

// Round 2
// 257.517 us; speedup vs baseline: 1.4242x; 1.4242x over previous
//
#include <hip/hip_runtime.h>
#include <stdint.h>

typedef __attribute__((ext_vector_type(4))) float f32x4;
typedef __attribute__((ext_vector_type(8))) float f32x8;
typedef __attribute__((ext_vector_type(16))) float f32x16;
typedef __attribute__((ext_vector_type(8))) short bf16x8;
typedef __attribute__((ext_vector_type(4))) short s16x4;
typedef __attribute__((ext_vector_type(4))) int i32x4;
typedef __attribute__((ext_vector_type(2))) int i32x2;

#define DEVI static __device__ __forceinline__

constexpr int CB  = 4;     // batch
constexpr int CS  = 2048;  // seq
constexpr int CH  = 16;    // heads
constexpr int CDH = 64;    // head dim
constexpr int CE  = 1024;  // embed

DEVI short f2bf(float x) {  // RNE float->bf16 (epilogue use)
  unsigned u = __float_as_uint(x);
  u += 0x7fffu + ((u >> 16) & 1u);
  return (short)(u >> 16);
}

DEVI int cvtpk(float lo, float hi) {  // packed f32x2 -> bf16x2 (RNE, 1 inst)
  int r;
  asm("v_cvt_pk_bf16_f32 %0, %1, %2" : "=v"(r) : "v"(lo), "v"(hi));
  return r;
}

DEVI float exp2v(float x) {  // raw v_exp_f32 (2^x)
  float r;
  asm("v_exp_f32 %0, %1" : "=v"(r) : "v"(x));
  return r;
}

DEVI void gload16(const void* g, void* l) {
  __builtin_amdgcn_global_load_lds(
      (const __attribute__((address_space(1))) void*)g,
      (__attribute__((address_space(3))) void*)l, 16, 0, 0);
}

DEVI f32x4 mfma16(bf16x8 a, bf16x8 b, f32x4 c) {
  return __builtin_amdgcn_mfma_f32_16x16x32_bf16(a, b, c, 0, 0, 0);
}
DEVI f32x16 mfma32(bf16x8 a, bf16x8 b, f32x16 c) {
  return __builtin_amdgcn_mfma_f32_32x32x16_bf16(a, b, c, 0, 0, 0);
}

DEVI float rmax16(f32x16 v) {
  f32x8 a = __builtin_shufflevector(v, v, 0, 1, 2, 3, 4, 5, 6, 7);
  f32x8 b = __builtin_shufflevector(v, v, 8, 9, 10, 11, 12, 13, 14, 15);
  a = __builtin_elementwise_max(a, b);
  f32x4 c = __builtin_shufflevector(a, a, 0, 1, 2, 3);
  f32x4 d = __builtin_shufflevector(a, a, 4, 5, 6, 7);
  c = __builtin_elementwise_max(c, d);
  return fmaxf(fmaxf(c[0], c[1]), fmaxf(c[2], c[3]));
}
DEVI float rsum16(f32x16 v) {
  f32x8 a = __builtin_shufflevector(v, v, 0, 1, 2, 3, 4, 5, 6, 7);
  f32x8 b = __builtin_shufflevector(v, v, 8, 9, 10, 11, 12, 13, 14, 15);
  a = a + b;
  f32x4 c = __builtin_shufflevector(a, a, 0, 1, 2, 3);
  f32x4 d = __builtin_shufflevector(a, a, 4, 5, 6, 7);
  c = c + d;
  return (c[0] + c[1]) + (c[2] + c[3]);
}

// ---------------- fp32 -> bf16 conversion passes ----------------

__global__ __launch_bounds__(256) void cvt_f32_bf16(
    const float* __restrict__ in, short* __restrict__ out, int n8) {
  int i = blockIdx.x * 256 + threadIdx.x;
  if (i >= n8) return;
  size_t o = (size_t)i * 8;
  f32x4 a = *(const f32x4*)&in[o];
  f32x4 b = *(const f32x4*)&in[o + 4];
  i32x4 p = {cvtpk(a[0], a[1]), cvtpk(a[2], a[3]),
             cvtpk(b[0], b[1]), cvtpk(b[2], b[3])};
  *(i32x4*)&out[o] = p;
}

__global__ __launch_bounds__(256) void cvtW3(
    const float* __restrict__ w0, const float* __restrict__ w1,
    const float* __restrict__ w2, short* __restrict__ o0,
    short* __restrict__ o1, short* __restrict__ o2) {
  const float* in = blockIdx.y == 0 ? w0 : (blockIdx.y == 1 ? w1 : w2);
  short* out = blockIdx.y == 0 ? o0 : (blockIdx.y == 1 ? o1 : o2);
  size_t o = ((size_t)blockIdx.x * 256 + threadIdx.x) * 8;
  f32x4 a = *(const f32x4*)&in[o];
  f32x4 b = *(const f32x4*)&in[o + 4];
  i32x4 p = {cvtpk(a[0], a[1]), cvtpk(a[2], a[3]),
             cvtpk(b[0], b[1]), cvtpk(b[2], b[3])};
  *(i32x4*)&out[o] = p;
}

// ---------------- GEMM: C = A(bf16) * W^T + bias ----------------
// WB16=1: W already bf16 (gload16 staging). WB16=0: W fp32, convert in-flight.
// MODE 0: out fp32 [M,N]; MODE 1: out bf16 [B,H,S,DH] scaled; MODE 2: [B,H,DH,S]
template<int MODE, int WB16>
__global__ __launch_bounds__(256) void gemm_bt(
    const short* __restrict__ Ap, const void* __restrict__ Wp,
    const float* __restrict__ bias, void* __restrict__ outp,
    int M, int N, int K, float scale) {
  __shared__ short As[128 * 32];
  __shared__ short Bs[128 * 32];
  const int t  = threadIdx.x;
  const int l  = t & 63;
  const int w  = t >> 6;
  const int g  = l >> 4;
  const int ln = l & 15;
  const int m0 = blockIdx.y * 128;
  const int n0 = blockIdx.x * 128;
  const int wr = (w >> 1) * 64;
  const int wc = (w & 1) * 64;

  f32x4 acc[4][4];
#pragma unroll
  for (int i = 0; i < 4; ++i)
#pragma unroll
    for (int j = 0; j < 4; ++j) acc[i][j] = {0.f, 0.f, 0.f, 0.f};

  for (int kt = 0; kt < K; kt += 32) {
#pragma unroll
    for (int il = 0; il < 2; ++il) {
      int o = (w * 2 + il) * 1024 + l * 16;
      int row = o >> 6, cb = o & 63;
      gload16((const char*)Ap + ((size_t)(m0 + row) * K + kt) * 2 + cb,
              (char*)As + o);
      if constexpr (WB16) {
        gload16((const char*)Wp + ((size_t)(n0 + row) * K + kt) * 2 + cb,
                (char*)Bs + o);
      }
    }
    if constexpr (!WB16) {
      const float* W = (const float*)Wp;
#pragma unroll
      for (int i = 0; i < 4; ++i) {
        int c = (i << 8) + t;
        int row = c >> 3, col = (c & 7) << 2;
        f32x4 v = *(const f32x4*)&W[(size_t)(n0 + row) * K + kt + col];
        i32x2 pw = {cvtpk(v[0], v[1]), cvtpk(v[2], v[3])};
        *(i32x2*)&Bs[row * 32 + col] = pw;
      }
    }
    __syncthreads();

    bf16x8 af[4], bfr[4];
#pragma unroll
    for (int mi = 0; mi < 4; ++mi)
      af[mi] = *(const bf16x8*)&As[(wr + mi * 16 + ln) * 32 + g * 8];
#pragma unroll
    for (int ni = 0; ni < 4; ++ni)
      bfr[ni] = *(const bf16x8*)&Bs[(wc + ni * 16 + ln) * 32 + g * 8];
#pragma unroll
    for (int mi = 0; mi < 4; ++mi)
#pragma unroll
      for (int ni = 0; ni < 4; ++ni)
        acc[mi][ni] = mfma16(af[mi], bfr[ni], acc[mi][ni]);
    __syncthreads();
  }

  // C/D (16x16): col = lane&15, row = (lane>>4)*4 + reg
#pragma unroll
  for (int mi = 0; mi < 4; ++mi)
#pragma unroll
    for (int ni = 0; ni < 4; ++ni)
#pragma unroll
      for (int r = 0; r < 4; ++r) {
        int row = m0 + wr + mi * 16 + g * 4 + r;
        int col = n0 + wc + ni * 16 + ln;
        float v = acc[mi][ni][r] + bias[col];
        if constexpr (MODE == 0) {
          ((float*)outp)[(size_t)row * N + col] = v;
        } else if constexpr (MODE == 1) {
          int b = row >> 11, s = row & 2047, h = col >> 6, d = col & 63;
          ((short*)outp)[(((size_t)(b * CH + h)) * CS + s) * CDH + d] =
              f2bf(v * scale);
        } else {
          int b = row >> 11, s = row & 2047, h = col >> 6, d = col & 63;
          ((short*)outp)[(((size_t)(b * CH + h)) * CDH + d) * CS + s] =
              f2bf(v * scale);
        }
      }
}

// ---------------- Flash attention, 32x32 MFMA, 64 q/wave ----------------
// q: [BH,S,DH] bf16 pre-scaled by log2e/8. k: [BH,S,DH]. vt: [BH,DH,S].
// out: [B,S,E] bf16. Swapped QK^T (mfma(K,Q)): lane holds 32 scores for its
// q-col (lane&31); P feeds PV A-operand with zero cross-lane movement.
// K LDS: natural rows, XOR-swizzled via pre-swizzled gload16 source.
// V LDS: kv-dim bit-permuted (pos = (k2,k3,k1,k0) in each 16-block) so the
// P-held kv set {16st+8b+4hi+j} reads as one contiguous b128.
__global__ __launch_bounds__(256, 2) void attn_fwd(
    const short* __restrict__ qp, const short* __restrict__ kp,
    const short* __restrict__ vtp, short* __restrict__ outp) {
  __shared__ short Ks[2][64 * 64];
  __shared__ short Vs[2][64 * 64];
  const int t = threadIdx.x, l = t & 63, w = t >> 6;
  const int lo = l & 31, hi = l >> 5;
  const int qb = blockIdx.x, bh = blockIdx.y, b = bh >> 4, h = bh & 15;
  const int swl = (lo & 7) << 4;

  // Q fragments: wave w owns q rows qb*256 + w*64 .. +63 (2 blocks of 32)
  const short* qbase = qp + ((size_t)bh * CS + qb * 256 + w * 64) * CDH;
  bf16x8 qf[2][4];
#pragma unroll
  for (int qk = 0; qk < 2; ++qk)
#pragma unroll
    for (int ks = 0; ks < 4; ++ks)
      qf[qk][ks] = *(const bf16x8*)&qbase[(qk * 32 + lo) * CDH + ks * 16 + hi * 8];

  // K staging: thread t DMAs 16B chunks (rows t>>3 and t>>3+32), src pre-swizzled
  const int krow = t >> 3, kcb = (t & 7) * 16;
  const char* ksrc = (const char*)kp + (size_t)bh * CS * 128 +
                     (size_t)krow * 128 + (kcb ^ ((krow & 7) << 4));
  // V staging (reg): thread t covers d-row t>>2, kv chunks (t&3) and (t&3)+4
  const int vrow = t >> 2, vc = t & 3;
  const char* vbase = (const char*)vtp + (size_t)bh * CDH * (CS * 2) +
                      (size_t)vrow * (CS * 2) + vc * 16;
  const int vsw = (vrow & 7) << 4;
  const int vgb = (vc >> 1) * 32 + (vc & 1) * 8;
  const int vw0 = vgb ^ vsw, vw1 = (vgb + 16) ^ vsw;
  const int vw2 = (vgb + 64) ^ vsw, vw3 = (vgb + 80) ^ vsw;

  f32x16 accO[2][2] = {};
  float mrun[2] = {-1e30f, -1e30f};
  float lrun[2] = {0.f, 0.f};

  // prologue: stage tile 0 into buf 0
  {
    gload16(ksrc, (char*)&Ks[0][0] + t * 16);
    gload16(ksrc + 4096, (char*)&Ks[0][0] + t * 16 + 4096);
    i32x4 v0 = *(const i32x4*)vbase;
    i32x4 v1 = *(const i32x4*)(vbase + 64);
    char* vd = (char*)&Vs[0][0] + vrow * 128;
    *(i32x2*)(vd + vw0) = __builtin_shufflevector(v0, v0, 0, 1);
    *(i32x2*)(vd + vw1) = __builtin_shufflevector(v0, v0, 2, 3);
    *(i32x2*)(vd + vw2) = __builtin_shufflevector(v1, v1, 0, 1);
    *(i32x2*)(vd + vw3) = __builtin_shufflevector(v1, v1, 2, 3);
  }
  __syncthreads();

#pragma unroll 2
  for (int tl = 0; tl < 32; ++tl) {
    const int cur = tl & 1, nxt = cur ^ 1;
    const char* Kc = (const char*)&Ks[cur][0];
    const char* Vc = (const char*)&Vs[cur][0];
    const bool last = (tl == 31);
    i32x4 v0, v1;
    if (!last) {  // issue next-tile loads early (T14)
      const char* ks2 = ksrc + (size_t)(tl + 1) * 8192;
      gload16(ks2, (char*)&Ks[nxt][0] + t * 16);
      gload16(ks2 + 4096, (char*)&Ks[nxt][0] + t * 16 + 4096);
      v0 = *(const i32x4*)(vbase + (size_t)(tl + 1) * 128);
      v1 = *(const i32x4*)(vbase + (size_t)(tl + 1) * 128 + 64);
    }

    // QK^T swapped: D[kv][q]; sc[qk][mb], lane col = q = qk*32+lo
    f32x16 sc[2][2] = {};
#pragma unroll
    for (int mb = 0; mb < 2; ++mb) {
      const char* krp = Kc + (mb * 32 + lo) * 128;
#pragma unroll
      for (int ks = 0; ks < 4; ++ks) {
        bf16x8 kf = *(const bf16x8*)(krp + ((ks * 32 + hi * 16) ^ swl));
        sc[0][mb] = mfma32(kf, qf[0][ks], sc[0][mb]);
        sc[1][mb] = mfma32(kf, qf[1][ks], sc[1][mb]);
      }
    }

    // online softmax (log2 domain), defer-max THR=12
    float pm0 = rmax16(__builtin_elementwise_max(sc[0][0], sc[0][1]));
    float pm1 = rmax16(__builtin_elementwise_max(sc[1][0], sc[1][1]));
    pm0 = fmaxf(pm0, __shfl_xor(pm0, 32, 64));
    pm1 = fmaxf(pm1, __shfl_xor(pm1, 32, 64));
    if (__any((pm0 > mrun[0] + 12.f) || (pm1 > mrun[1] + 12.f))) {
      float mn0 = fmaxf(mrun[0], pm0), mn1 = fmaxf(mrun[1], pm1);
      float fc0 = exp2v(mrun[0] - mn0), fc1 = exp2v(mrun[1] - mn1);
      f32x16 fv0, fv1;
#pragma unroll
      for (int r = 0; r < 16; ++r) {
        int src = (r & 3) + 8 * (r >> 2) + 4 * hi;
        fv0[r] = __shfl(fc0, src, 64);
        fv1[r] = __shfl(fc1, src, 64);
      }
      accO[0][0] *= fv0; accO[0][1] *= fv0;
      accO[1][0] *= fv1; accO[1][1] *= fv1;
      lrun[0] *= fc0; lrun[1] *= fc1;
      mrun[0] = mn0; mrun[1] = mn1;
    }
    f32x16 pe[2][2];
#pragma unroll
    for (int qk = 0; qk < 2; ++qk)
#pragma unroll
      for (int mb = 0; mb < 2; ++mb)
#pragma unroll
        for (int i = 0; i < 16; ++i)
          pe[qk][mb][i] = exp2v(sc[qk][mb][i] - mrun[qk]);
    float ls0 = rsum16(pe[0][0] + pe[0][1]);
    float ls1 = rsum16(pe[1][0] + pe[1][1]);
    ls0 += __shfl_xor(ls0, 32, 64);
    ls1 += __shfl_xor(ls1, 32, 64);
    lrun[0] += ls0;
    lrun[1] += ls1;

    // pack P -> bf16 A-fragments: frag[kst] slot s <-> pe[kst>>1][(kst&1)*8+s]
    bf16x8 pf[2][4];
#pragma unroll
    for (int qk = 0; qk < 2; ++qk)
#pragma unroll
      for (int kst = 0; kst < 4; ++kst) {
        const int mb = kst >> 1, o8 = (kst & 1) * 8;
        i32x4 pw = {cvtpk(pe[qk][mb][o8 + 0], pe[qk][mb][o8 + 1]),
                    cvtpk(pe[qk][mb][o8 + 2], pe[qk][mb][o8 + 3]),
                    cvtpk(pe[qk][mb][o8 + 4], pe[qk][mb][o8 + 5]),
                    cvtpk(pe[qk][mb][o8 + 6], pe[qk][mb][o8 + 7])};
        pf[qk][kst] = __builtin_bit_cast(bf16x8, pw);
      }

    // PV: D[q][d]; B = permuted Vt rows
#pragma unroll
    for (int nb = 0; nb < 2; ++nb) {
      const char* vrp = Vc + (nb * 32 + lo) * 128;
#pragma unroll
      for (int kst = 0; kst < 4; ++kst) {
        bf16x8 vf = *(const bf16x8*)(vrp + ((kst * 32 + hi * 16) ^ swl));
        accO[0][nb] = mfma32(pf[0][kst], vf, accO[0][nb]);
        accO[1][nb] = mfma32(pf[1][kst], vf, accO[1][nb]);
      }
    }

    if (!last) {  // write next V tile (loads have landed under compute)
      char* vd = (char*)&Vs[nxt][0] + vrow * 128;
      *(i32x2*)(vd + vw0) = __builtin_shufflevector(v0, v0, 0, 1);
      *(i32x2*)(vd + vw1) = __builtin_shufflevector(v0, v0, 2, 3);
      *(i32x2*)(vd + vw2) = __builtin_shufflevector(v1, v1, 0, 1);
      *(i32x2*)(vd + vw3) = __builtin_shufflevector(v1, v1, 2, 3);
    }
    __syncthreads();
  }

  // epilogue: normalize and store
#pragma unroll
  for (int qk = 0; qk < 2; ++qk) {
    float inv = 1.f / lrun[qk];
    f32x16 iv;
#pragma unroll
    for (int r = 0; r < 16; ++r)
      iv[r] = __shfl(inv, (r & 3) + 8 * (r >> 2) + 4 * hi, 64);
#pragma unroll
    for (int nb = 0; nb < 2; ++nb) {
      f32x16 val = accO[qk][nb] * iv;
#pragma unroll
      for (int r = 0; r < 16; ++r) {
        int sg = qb * 256 + w * 64 + qk * 32 + (r & 3) + 8 * (r >> 2) + 4 * hi;
        outp[((size_t)(b * CS + sg)) * CE + h * CDH + nb * 32 + lo] =
            f2bf(val[r]);
      }
    }
  }
}

extern "C" void kernel_launch(void* const* d_in, const int* in_sizes, int n_in,
                              void* d_out, int out_size, void* d_ws,
                              size_t ws_size, hipStream_t stream) {
  const float* queries = (const float*)d_in[0];
  const float* keys    = (const float*)d_in[1];
  const float* values  = (const float*)d_in[2];
  const float* Wq = (const float*)d_in[3];
  const float* bq = (const float*)d_in[4];
  const float* Wk = (const float*)d_in[5];
  const float* bk = (const float*)d_in[6];
  const float* Wv = (const float*)d_in[7];
  const float* bv = (const float*)d_in[8];
  const float* Wo = (const float*)d_in[9];
  const float* bo = (const float*)d_in[10];

  const size_t NELT = (size_t)CB * CS * CE;  // 8388608
  short* R1  = (short*)d_ws;        // X16 scratch, later attn output
  short* qp  = R1 + NELT;
  short* kp  = qp + NELT;
  short* vtp = kp + NELT;
  // W16 scratch lives in d_out (dead until the final GEMM overwrites it)
  short* w16q = (short*)d_out;
  short* w16k = w16q + (size_t)CE * CE;
  short* w16v = w16k + (size_t)CE * CE;

  dim3 blk(256);
  dim3 gproj(CE / 128, (CB * CS) / 128);  // (8, 64)
  const int n8x = (int)(NELT / 8);        // 1048576
  const float qscale = 0.18033688011112042f;  // log2(e) / sqrt(DH)

  cvtW3<<<dim3(512, 3), blk, 0, stream>>>(Wq, Wk, Wv, w16q, w16k, w16v);
  cvt_f32_bf16<<<4096, blk, 0, stream>>>(queries, R1, n8x);
  gemm_bt<1, 1><<<gproj, blk, 0, stream>>>(R1, w16q, bq, qp,
                                           CB * CS, CE, CE, qscale);
  cvt_f32_bf16<<<4096, blk, 0, stream>>>(keys, R1, n8x);
  gemm_bt<1, 1><<<gproj, blk, 0, stream>>>(R1, w16k, bk, kp,
                                           CB * CS, CE, CE, 1.0f);
  cvt_f32_bf16<<<4096, blk, 0, stream>>>(values, R1, n8x);
  gemm_bt<2, 1><<<gproj, blk, 0, stream>>>(R1, w16v, bv, vtp,
                                           CB * CS, CE, CE, 1.0f);
  attn_fwd<<<dim3(CS / 256, CB * CH), blk, 0, stream>>>(qp, kp, vtp, R1);
  gemm_bt<0, 0><<<gproj, blk, 0, stream>>>(R1, Wo, bo, (float*)d_out,
                                           CB * CS, CE, CE, 1.0f);
}